// Round 1
// baseline (180.513 us; speedup 1.0000x reference)
//
#include <hip/hip_runtime.h>
#include <hip/hip_bf16.h>

typedef __attribute__((ext_vector_type(4))) float f32x4;
typedef __attribute__((ext_vector_type(8))) short bf16x8;
typedef __attribute__((ext_vector_type(4))) short bf16x4;

#define DEV static __device__ __forceinline__

constexpr float LOG2E  = 1.4426950408889634f;
constexpr float QSCALE = 0.17677669529663687f * LOG2E;  // hd^-0.5 * log2e

// ws layout (bytes)
constexpr size_t OFF_Q   = 0;            // bf16 (B*H, N, 32) row-major, pre-scaled
constexpr size_t OFF_K   = 8u  << 20;    // bf16 (B*H, N, 32)
constexpr size_t OFF_VT  = 16u << 20;    // bf16 (B*H, 32, N)  (transposed V)
constexpr size_t OFF_RPB = 24u << 20;    // f32  (H, N, N), pre-multiplied by log2e
constexpr size_t OFF_AO  = 28u << 20;    // bf16 (B*N, C) attention output
constexpr size_t OFF_POS = 36u << 20;    // f32  (3375, 4)
constexpr size_t OFF_WQ  = 37u << 20;    // bf16 (384, 128)
constexpr size_t OFF_WP  = 38u << 20;    // bf16 (128, 128)

DEV short f2b(float f) {
  union { __bf16 h; short s; } u;
  u.h = (__bf16)f;
  return u.s;
}

// ---------------- K0: weight convert ----------------
__global__ void ca_convw(const float* __restrict__ qkv_w,
                         const float* __restrict__ proj_w,
                         short* __restrict__ wq, short* __restrict__ wp) {
  int i = blockIdx.x * 256 + threadIdx.x;  // 65536 threads
  if (i < 49152) {
    float f = qkv_w[i];
    if (i < 16384) f *= QSCALE;  // q rows: fold scale*log2e
    wq[i] = f2b(f);
  } else {
    int j = i - 49152;
    wp[j] = f2b(proj_w[j]);
  }
}

// ---------------- K1: DynamicPosBias MLP ----------------
DEV void ln_relu8(const float* v, const float* __restrict__ g,
                  const float* __restrict__ b, float* t) {
  float m = 0.f;
#pragma unroll
  for (int i = 0; i < 8; i++) m += v[i];
  m *= 0.125f;
  float var = 0.f;
#pragma unroll
  for (int i = 0; i < 8; i++) { float d = v[i] - m; var += d * d; }
  var *= 0.125f;
  float inv = 1.0f / sqrtf(var + 1e-5f);
#pragma unroll
  for (int i = 0; i < 8; i++) {
    float u = (v[i] - m) * inv * g[i] + b[i];
    t[i] = u > 0.f ? u : 0.f;
  }
}

DEV void mm8(const float* t, const float* __restrict__ w,
             const float* __restrict__ c, float* o) {
#pragma unroll
  for (int oo = 0; oo < 8; oo++) {
    float a = c[oo];
#pragma unroll
    for (int i = 0; i < 8; i++) a += t[i] * w[oo * 8 + i];
    o[oo] = a;
  }
}

__global__ void ca_posmlp(
    const float* __restrict__ pw, const float* __restrict__ pb,
    const float* __restrict__ g1, const float* __restrict__ b1,
    const float* __restrict__ w1, const float* __restrict__ c1,
    const float* __restrict__ g2, const float* __restrict__ b2,
    const float* __restrict__ w2, const float* __restrict__ c2,
    const float* __restrict__ g3, const float* __restrict__ b3,
    const float* __restrict__ w3, const float* __restrict__ c3,
    float* __restrict__ pos_out) {
  int r = blockIdx.x * 64 + threadIdx.x;
  if (r >= 3375) return;
  float x0 = (float)(r / 225 - 7);
  float x1 = (float)((r / 15) % 15 - 7);
  float x2 = (float)(r % 15 - 7);
  float v[8], t[8], u[8];
#pragma unroll
  for (int o = 0; o < 8; o++)
    v[o] = x0 * pw[o * 3] + x1 * pw[o * 3 + 1] + x2 * pw[o * 3 + 2] + pb[o];
  ln_relu8(v, g1, b1, t);
  mm8(t, w1, c1, u);
  ln_relu8(u, g2, b2, t);
  mm8(t, w2, c2, v);
  ln_relu8(v, g3, b3, t);
#pragma unroll
  for (int hh = 0; hh < 4; hh++) {
    float a = c3[hh];
#pragma unroll
    for (int i = 0; i < 8; i++) a += t[i] * w3[hh * 8 + i];
    pos_out[r * 4 + hh] = a * LOG2E;  // log2 domain for exp2-softmax
  }
}

// ---------------- K2: expand rpb table (H,N,N) f32 ----------------
__global__ void ca_rpb(const float* __restrict__ pos, float* __restrict__ rpb) {
  int gid = blockIdx.x * 256 + threadIdx.x;  // 262144 threads = (i,j)
  int i = gid >> 9, j = gid & 511;
  int rh = (i >> 6) - (j >> 6) + 7;
  int rw = ((i >> 3) & 7) - ((j >> 3) & 7) + 7;
  int rd = (i & 7) - (j & 7) + 7;
  int idx = (rh * 15 + rw) * 15 + rd;
  f32x4 p = *(const f32x4*)(pos + idx * 4);
#pragma unroll
  for (int hh = 0; hh < 4; hh++) rpb[hh * 262144 + gid] = p[hh];
}

// ---------------- K3: QKV projection ----------------
// z=0: x -> q (row-major, pre-scaled); z=1: y -> k (row-major); z=2: y -> vT
__global__ __launch_bounds__(256) void ca_qkv(
    const float* __restrict__ x, const float* __restrict__ y,
    const short* __restrict__ wq, const float* __restrict__ qkv_b,
    short* __restrict__ qbuf, short* __restrict__ kbuf, short* __restrict__ vtbuf) {
  __shared__ short lds[64 * 136];  // 64 tokens x 128 k, stride 136 (272B) anti-conflict
  const int z = blockIdx.y;
  const float* __restrict__ in = (z == 0) ? x : y;
  const int t0 = blockIdx.x * 64;
  const int tid = threadIdx.x;
  {
    const int tr = tid >> 2, kb = (tid & 3) * 32;
    const float* src = in + (size_t)(t0 + tr) * 128 + kb;
    short* dst = lds + tr * 136 + kb;
#pragma unroll
    for (int kk = 0; kk < 8; kk++) {
      f32x4 f = *(const f32x4*)(src + kk * 4);
      bf16x4 hv;
#pragma unroll
      for (int e = 0; e < 4; e++) hv[e] = f2b(f[e]);
      *(bf16x4*)(dst + kk * 4) = hv;
    }
  }
  __syncthreads();
  const int w = tid >> 6, lane = tid & 63, lr = lane & 15, lg = lane >> 4;
  bf16x8 afrag[4];
  const short* ap = lds + (w * 16 + lr) * 136 + lg * 8;
#pragma unroll
  for (int k4 = 0; k4 < 4; k4++) afrag[k4] = *(const bf16x8*)(ap + k4 * 32);

  const int tokbase = t0 + w * 16 + lg * 4;
  const int b_ = tokbase >> 9;
  const int n = tokbase & 511;

#pragma unroll
  for (int ct = 0; ct < 8; ct++) {
    const int col = z * 128 + ct * 16;
    float bias = qkv_b[col + lr];
    if (z == 0) bias *= QSCALE;
    f32x4 acc = {bias, bias, bias, bias};
    const short* bp = wq + (col + lr) * 128 + lg * 8;
#pragma unroll
    for (int k4 = 0; k4 < 4; k4++) {
      bf16x8 bfr = *(const bf16x8*)(bp + k4 * 32);
      acc = __builtin_amdgcn_mfma_f32_16x16x32_bf16(afrag[k4], bfr, acc, 0, 0, 0);
    }
    const int lc = ct * 16 + lr;      // local col 0..127
    const int d = lc & 31, hh = lc >> 5;
    if (z == 2) {
      bf16x4 ov;
#pragma unroll
      for (int r = 0; r < 4; r++) ov[r] = f2b(acc[r]);
      *(bf16x4*)(vtbuf + (size_t)(b_ * 4 + hh) * 16384 + d * 512 + n) = ov;
    } else {
      short* op = (z == 0 ? qbuf : kbuf) + ((size_t)(b_ * 4 + hh) * 512 + n) * 32 + d;
#pragma unroll
      for (int r = 0; r < 4; r++) op[r * 32] = f2b(acc[r]);
    }
  }
}

// ---------------- K4: fused attention ----------------
// block = 4 waves; wave owns 16 q-rows; full 512 scores in regs (no online SM).
// Computes S^T = mfma(K, Q) with rpb as MFMA C-in; lane owns q = lane&15.
__global__ __launch_bounds__(256) void ca_attn(
    const short* __restrict__ qbuf, const short* __restrict__ kbuf,
    const short* __restrict__ vtbuf, const float* __restrict__ rpb,
    short* __restrict__ aobuf) {
  __shared__ short ptile[4][16 * 40];  // per-wave 16x32 bf16, stride 40 (80B)
  const int bid = blockIdx.x;
  const int b_ = bid >> 5, hh = (bid >> 3) & 3, qt = bid & 7;
  const int bh = b_ * 4 + hh;
  const int tid = threadIdx.x;
  const int w = tid >> 6, lane = tid & 63, lr = lane & 15, lg = lane >> 4;
  const int q0 = qt * 64 + w * 16;

  const short* qp = qbuf + (size_t)bh * 16384 + q0 * 32;
  bf16x8 qf = *(const bf16x8*)(qp + lr * 32 + lg * 8);
  const short* kp = kbuf + (size_t)bh * 16384;
  const float* biasp = rpb + (size_t)hh * 262144 + (q0 + lr) * 512 + lg * 4;

  f32x4 acc[32];
#pragma unroll
  for (int t = 0; t < 32; t++) {
    f32x4 cin = *(const f32x4*)(biasp + t * 16);
    bf16x8 kf = *(const bf16x8*)(kp + (t * 16 + lr) * 32 + lg * 8);
    acc[t] = __builtin_amdgcn_mfma_f32_16x16x32_bf16(kf, qf, cin, 0, 0, 0);
  }

  // row max (lane's q = q0 + lr; its j's = t*16 + lg*4 + r)
  float m = -3.0e38f;
#pragma unroll
  for (int t = 0; t < 32; t++)
#pragma unroll
    for (int r = 0; r < 4; r++) m = fmaxf(m, acc[t][r]);
  m = fmaxf(m, __shfl_xor(m, 16));
  m = fmaxf(m, __shfl_xor(m, 32));

  float s = 0.f;
#pragma unroll
  for (int t = 0; t < 32; t++)
#pragma unroll
    for (int r = 0; r < 4; r++) {
      float p = exp2f(acc[t][r] - m);
      acc[t][r] = p;
      s += p;
    }
  s += __shfl_xor(s, 16);
  s += __shfl_xor(s, 32);
  float inv = 1.0f / s;

  const short* vp = vtbuf + (size_t)bh * 16384;
  short* myt = &ptile[w][0];
  f32x4 oacc0 = {0.f, 0.f, 0.f, 0.f}, oacc1 = {0.f, 0.f, 0.f, 0.f};
#pragma unroll
  for (int cc = 0; cc < 16; cc++) {  // 32-wide j chunks
    bf16x4 pa, pb2;
#pragma unroll
    for (int r = 0; r < 4; r++) {
      pa[r]  = f2b(acc[2 * cc][r]);
      pb2[r] = f2b(acc[2 * cc + 1][r]);
    }
    *(bf16x4*)(myt + lr * 40 + lg * 4) = pa;            // j_local = lg*4 + r
    *(bf16x4*)(myt + lr * 40 + 16 + lg * 4) = pb2;      // j_local = 16 + lg*4 + r
    __syncthreads();
    bf16x8 paf = *(const bf16x8*)(myt + lr * 40 + lg * 8);
    bf16x8 v0 = *(const bf16x8*)(vp + lr * 512 + cc * 32 + lg * 8);
    bf16x8 v1 = *(const bf16x8*)(vp + (16 + lr) * 512 + cc * 32 + lg * 8);
    oacc0 = __builtin_amdgcn_mfma_f32_16x16x32_bf16(paf, v0, oacc0, 0, 0, 0);
    oacc1 = __builtin_amdgcn_mfma_f32_16x16x32_bf16(paf, v1, oacc1, 0, 0, 0);
  }

#pragma unroll
  for (int r = 0; r < 4; r++) {
    float iv = __shfl(inv, lg * 4 + r);  // inv for q' = lg*4 + r (lanes 0..15 hold it)
    int row = b_ * 512 + q0 + lg * 4 + r;
    aobuf[(size_t)row * 128 + hh * 32 + lr]      = f2b(oacc0[r] * iv);
    aobuf[(size_t)row * 128 + hh * 32 + 16 + lr] = f2b(oacc1[r] * iv);
  }
}

// ---------------- K5: output projection ----------------
__global__ __launch_bounds__(256) void ca_proj(
    const short* __restrict__ aobuf, const short* __restrict__ wp,
    const float* __restrict__ proj_b, float* __restrict__ out) {
  const int t0 = blockIdx.x * 64;
  const int tid = threadIdx.x;
  const int w = tid >> 6, lane = tid & 63, lr = lane & 15, lg = lane >> 4;
  const short* ap = aobuf + (size_t)(t0 + w * 16 + lr) * 128 + lg * 8;
  bf16x8 afrag[4];
#pragma unroll
  for (int k4 = 0; k4 < 4; k4++) afrag[k4] = *(const bf16x8*)(ap + k4 * 32);
#pragma unroll
  for (int ct = 0; ct < 8; ct++) {
    float bias = proj_b[ct * 16 + lr];
    f32x4 acc = {bias, bias, bias, bias};
    const short* bp = wp + (ct * 16 + lr) * 128 + lg * 8;
#pragma unroll
    for (int k4 = 0; k4 < 4; k4++) {
      bf16x8 bfr = *(const bf16x8*)(bp + k4 * 32);
      acc = __builtin_amdgcn_mfma_f32_16x16x32_bf16(afrag[k4], bfr, acc, 0, 0, 0);
    }
#pragma unroll
    for (int r = 0; r < 4; r++)
      out[(size_t)(t0 + w * 16 + lg * 4 + r) * 128 + ct * 16 + lr] = acc[r];
  }
}

extern "C" void kernel_launch(void* const* d_in, const int* in_sizes, int n_in,
                              void* d_out, int out_size, void* d_ws, size_t ws_size,
                              hipStream_t stream) {
  const float* x      = (const float*)d_in[0];
  const float* y      = (const float*)d_in[1];
  const float* qkv_w  = (const float*)d_in[5];
  const float* qkv_b  = (const float*)d_in[6];
  const float* proj_w = (const float*)d_in[7];
  const float* proj_b = (const float*)d_in[8];
  const float* pos_w  = (const float*)d_in[9];
  const float* pos_b  = (const float*)d_in[10];
  const float* ln1g = (const float*)d_in[11];
  const float* ln1b = (const float*)d_in[12];
  const float* p1w  = (const float*)d_in[13];
  const float* p1b  = (const float*)d_in[14];
  const float* ln2g = (const float*)d_in[15];
  const float* ln2b = (const float*)d_in[16];
  const float* p2w  = (const float*)d_in[17];
  const float* p2b  = (const float*)d_in[18];
  const float* ln3g = (const float*)d_in[19];
  const float* ln3b = (const float*)d_in[20];
  const float* p3w  = (const float*)d_in[21];
  const float* p3b  = (const float*)d_in[22];
  float* out = (float*)d_out;

  char* ws = (char*)d_ws;
  short* qbuf  = (short*)(ws + OFF_Q);
  short* kbuf  = (short*)(ws + OFF_K);
  short* vtbuf = (short*)(ws + OFF_VT);
  float* rpb   = (float*)(ws + OFF_RPB);
  short* aobuf = (short*)(ws + OFF_AO);
  float* posb  = (float*)(ws + OFF_POS);
  short* wq    = (short*)(ws + OFF_WQ);
  short* wp    = (short*)(ws + OFF_WP);

  ca_convw<<<256, 256, 0, stream>>>(qkv_w, proj_w, wq, wp);
  ca_posmlp<<<53, 64, 0, stream>>>(pos_w, pos_b, ln1g, ln1b, p1w, p1b,
                                   ln2g, ln2b, p2w, p2b, ln3g, ln3b, p3w, p3b, posb);
  ca_rpb<<<1024, 256, 0, stream>>>(posb, rpb);
  ca_qkv<<<dim3(512, 3), 256, 0, stream>>>(x, y, wq, qkv_b, qbuf, kbuf, vtbuf);
  ca_attn<<<2048, 256, 0, stream>>>(qbuf, kbuf, vtbuf, rpb, aobuf);
  ca_proj<<<512, 256, 0, stream>>>(aobuf, wp, proj_b, out);
}

// Round 2
// 111.302 us; speedup vs baseline: 1.6218x; 1.6218x over previous
//
#include <hip/hip_runtime.h>
#include <hip/hip_bf16.h>

typedef __attribute__((ext_vector_type(4))) float f32x4;
typedef __attribute__((ext_vector_type(8))) short bf16x8;
typedef __attribute__((ext_vector_type(4))) short bf16x4;
typedef __attribute__((ext_vector_type(2))) unsigned int u32x2;

#define DEV static __device__ __forceinline__

constexpr float LOG2E  = 1.4426950408889634f;
constexpr float QSCALE = 0.17677669529663687f * LOG2E;  // hd^-0.5 * log2e

// ws layout (bytes)
constexpr size_t OFF_Q   = 0;                    // bf16 frag-order Q  (256 bh x 32 qg x 512)
constexpr size_t OFF_K   = (size_t)8  << 20;     // bf16 frag-order K  (256 bh x 32 t  x 512)
constexpr size_t OFF_V   = (size_t)16 << 20;     // bf16 frag-order V  (256 bh x 16jc x 2dh x 512)
constexpr size_t OFF_RPB = (size_t)24 << 20;     // bf16 (H, N, N), pre-multiplied by log2e
constexpr size_t OFF_AO  = (size_t)26 << 20;     // bf16 head-major (bh, n, 32)
constexpr size_t OFF_POS = (size_t)34 << 20;     // f32  (3375, 4)
constexpr size_t OFF_WQ  = (size_t)35 << 20;     // bf16 (384, 128)
constexpr size_t OFF_WP  = (size_t)36 << 20;     // bf16 (128, 128)

DEV short f2b(float f) {
  union { __bf16 h; short s; } u;
  u.h = (__bf16)f;
  return u.s;
}
DEV float b2f(unsigned int u) {
  union { unsigned int u; float f; } x; x.u = u; return x.f;
}
DEV unsigned int pkbf(float a, float b) {
  union { __bf16 h; unsigned short s; } ua, ub;
  ua.h = (__bf16)a; ub.h = (__bf16)b;
  return (unsigned int)ua.s | ((unsigned int)ub.s << 16);
}

// ---------------- K0: weight convert ----------------
__global__ void ca_convw(const float* __restrict__ qkv_w,
                         const float* __restrict__ proj_w,
                         short* __restrict__ wq, short* __restrict__ wp) {
  int i = blockIdx.x * 256 + threadIdx.x;  // 65536 threads
  if (i < 49152) {
    float f = qkv_w[i];
    if (i < 16384) f *= QSCALE;  // q rows: fold scale*log2e
    wq[i] = f2b(f);
  } else {
    int j = i - 49152;
    wp[j] = f2b(proj_w[j]);
  }
}

// ---------------- K1: DynamicPosBias MLP ----------------
DEV void ln_relu8(const float* v, const float* __restrict__ g,
                  const float* __restrict__ b, float* t) {
  float m = 0.f;
#pragma unroll
  for (int i = 0; i < 8; i++) m += v[i];
  m *= 0.125f;
  float var = 0.f;
#pragma unroll
  for (int i = 0; i < 8; i++) { float d = v[i] - m; var += d * d; }
  var *= 0.125f;
  float inv = 1.0f / sqrtf(var + 1e-5f);
#pragma unroll
  for (int i = 0; i < 8; i++) {
    float u = (v[i] - m) * inv * g[i] + b[i];
    t[i] = u > 0.f ? u : 0.f;
  }
}

DEV void mm8(const float* t, const float* __restrict__ w,
             const float* __restrict__ c, float* o) {
#pragma unroll
  for (int oo = 0; oo < 8; oo++) {
    float a = c[oo];
#pragma unroll
    for (int i = 0; i < 8; i++) a += t[i] * w[oo * 8 + i];
    o[oo] = a;
  }
}

__global__ void ca_posmlp(
    const float* __restrict__ pw, const float* __restrict__ pb,
    const float* __restrict__ g1, const float* __restrict__ b1,
    const float* __restrict__ w1, const float* __restrict__ c1,
    const float* __restrict__ g2, const float* __restrict__ b2,
    const float* __restrict__ w2, const float* __restrict__ c2,
    const float* __restrict__ g3, const float* __restrict__ b3,
    const float* __restrict__ w3, const float* __restrict__ c3,
    float* __restrict__ pos_out) {
  int r = blockIdx.x * 64 + threadIdx.x;
  if (r >= 3375) return;
  float x0 = (float)(r / 225 - 7);
  float x1 = (float)((r / 15) % 15 - 7);
  float x2 = (float)(r % 15 - 7);
  float v[8], t[8], u[8];
#pragma unroll
  for (int o = 0; o < 8; o++)
    v[o] = x0 * pw[o * 3] + x1 * pw[o * 3 + 1] + x2 * pw[o * 3 + 2] + pb[o];
  ln_relu8(v, g1, b1, t);
  mm8(t, w1, c1, u);
  ln_relu8(u, g2, b2, t);
  mm8(t, w2, c2, v);
  ln_relu8(v, g3, b3, t);
#pragma unroll
  for (int hh = 0; hh < 4; hh++) {
    float a = c3[hh];
#pragma unroll
    for (int i = 0; i < 8; i++) a += t[i] * w3[hh * 8 + i];
    pos_out[r * 4 + hh] = a * LOG2E;  // log2 domain for exp2-softmax
  }
}

// ---------------- K2: expand rpb table (H,N,N) bf16 ----------------
__global__ void ca_rpb(const float* __restrict__ pos, short* __restrict__ rpbh) {
  int gid = blockIdx.x * 256 + threadIdx.x;  // 4h * 512q * 128 jgroups
  int jg = gid & 127, q = (gid >> 7) & 511, hh = gid >> 16;
  int j0 = jg * 4;
  bf16x4 outv;
#pragma unroll
  for (int r = 0; r < 4; r++) {
    int j = j0 + r;
    int rh = (q >> 6) - (j >> 6) + 7;
    int rw = ((q >> 3) & 7) - ((j >> 3) & 7) + 7;
    int rd = (q & 7) - (j & 7) + 7;
    int idx = (rh * 15 + rw) * 15 + rd;
    outv[r] = f2b(pos[idx * 4 + hh]);
  }
  *(bf16x4*)(rpbh + ((size_t)(hh * 512 + q) * 512) + j0) = outv;
}

// ---------------- K3: QKV projection -> frag-order Q/K/V ----------------
// z=0: x -> qfrag; z=1: y -> kfrag + vfrag
__global__ __launch_bounds__(256) void ca_qkv(
    const float* __restrict__ x, const float* __restrict__ y,
    const short* __restrict__ wq, const float* __restrict__ qkv_b,
    short* __restrict__ gq, short* __restrict__ gk, short* __restrict__ gv) {
  __shared__ short lds[16384];  // 32KB: input stage, then frag relayout
  const int z = blockIdx.y;
  const int t0 = blockIdx.x * 64;
  const int b_ = t0 >> 9;
  const int n0 = t0 & 511;
  const int tid = threadIdx.x;
  const float* __restrict__ in = (z == 0) ? x : y;
  {
    const int tr = tid >> 2, kb = (tid & 3) * 32;
    const float* src = in + (size_t)(t0 + tr) * 128 + kb;
    short* dst = lds + tr * 136 + kb;
#pragma unroll
    for (int kk = 0; kk < 8; kk++) {
      f32x4 f = *(const f32x4*)(src + kk * 4);
      bf16x4 hv;
#pragma unroll
      for (int e = 0; e < 4; e++) hv[e] = f2b(f[e]);
      *(bf16x4*)(dst + kk * 4) = hv;
    }
  }
  __syncthreads();
  const int w = tid >> 6, lane = tid & 63, lr = lane & 15, lg = lane >> 4;
  bf16x8 afrag[4];
  {
    const short* ap = lds + (w * 16 + lr) * 136 + lg * 8;
#pragma unroll
    for (int k4 = 0; k4 < 4; k4++) afrag[k4] = *(const bf16x8*)(ap + k4 * 32);
  }
  __syncthreads();  // all afrag reads done before relayout overwrites lds

  const int nct = z ? 16 : 8;
  for (int ct = 0; ct < nct; ct++) {
    const int col = z * 128 + ct * 16;
    float bias = qkv_b[col + lr];
    if (z == 0) bias *= QSCALE;
    f32x4 acc = {bias, bias, bias, bias};
    const short* bp = wq + (size_t)(col + lr) * 128 + lg * 8;
#pragma unroll
    for (int k4 = 0; k4 < 4; k4++) {
      bf16x8 bfr = *(const bf16x8*)(bp + k4 * 32);
      acc = __builtin_amdgcn_mfma_f32_16x16x32_bf16(afrag[k4], bfr, acc, 0, 0, 0);
    }
    // acc[r] = out[token = t0 + w*16 + lg*4 + r][col + lr]
    if (z == 1 && ct >= 8) {  // V: frag chunk ((w>>1)*8 + hv*2 + dh), lane_v=(d&15)+16*(j5>>3), e=j5&7
      const int hv_ = (ct - 8) >> 1;
      const int d = ((ct - 8) & 1) * 16 + lr;
      const int base = 8192 + ((w >> 1) * 8 + hv_ * 2 + (d >> 4)) * 512 + (d & 15) * 8;
#pragma unroll
      for (int r = 0; r < 4; r++) {
        int j5 = (w & 1) * 16 + lg * 4 + r;
        lds[base + (j5 >> 3) * 128 + (j5 & 7)] = f2b(acc[r]);
      }
    } else {  // Q or K: frag chunk (w*4 + h), lane=(n&15)+16*(d>>3), e=d&7
      const int d = (ct & 1) * 16 + lr;
      const int base = (w * 4 + (ct >> 1)) * 512 + 128 * (d >> 3) + (d & 7);
#pragma unroll
      for (int r = 0; r < 4; r++)
        lds[base + (lg * 4 + r) * 8] = f2b(acc[r]);
    }
  }
  __syncthreads();
  // cooperative 1KB-per-wave coalesced chunk stores
  if (z == 0) {
#pragma unroll
    for (int kk = 0; kk < 4; kk++) {
      const int c = kk * 4 + w, hh = c & 3, wq_ = c >> 2;
      bf16x8 vd = *(const bf16x8*)(lds + c * 512 + lane * 8);
      *(bf16x8*)(gq + (((size_t)b_ * 4 + hh) * 32 + (n0 >> 4) + wq_) * 512 + lane * 8) = vd;
    }
  } else {
#pragma unroll
    for (int kk = 0; kk < 4; kk++) {
      const int c = kk * 4 + w, hh = c & 3, wk_ = c >> 2;
      bf16x8 vd = *(const bf16x8*)(lds + c * 512 + lane * 8);
      *(bf16x8*)(gk + (((size_t)b_ * 4 + hh) * 32 + (n0 >> 4) + wk_) * 512 + lane * 8) = vd;
    }
#pragma unroll
    for (int kk = 0; kk < 4; kk++) {
      const int c = kk * 4 + w, jcl = c >> 3, hh = (c >> 1) & 3, dh = c & 1;
      bf16x8 vd = *(const bf16x8*)(lds + 8192 + c * 512 + lane * 8);
      *(bf16x8*)(gv + ((((size_t)b_ * 4 + hh) * 16 + (n0 >> 5) + jcl) * 2 + dh) * 512 + lane * 8) = vd;
    }
  }
}

// ---------------- K4: fused attention (flash-style, frag-order K/V) ----------------
DEV void stage_kv(const short* kg, const short* vg, short* buf, int T, int w, int lane) {
#pragma unroll
  for (int i = 0; i < 4; i++) {
    const int c = w * 4 + i;  // waves 0,1 stage K chunks 0..7; waves 2,3 stage V chunks 0..7
    const short* src;
    short* dst;
    if (c < 8) {
      src = kg + ((size_t)(T * 8 + c)) * 512 + lane * 8;
      dst = buf + c * 512;
    } else {
      src = vg + ((size_t)(T * 8 + c - 8)) * 512 + lane * 8;
      dst = buf + 4096 + (c - 8) * 512;
    }
    __builtin_amdgcn_global_load_lds((const __attribute__((address_space(1))) void*)src,
                                     (__attribute__((address_space(3))) void*)dst, 16, 0, 0);
  }
}

__global__ __launch_bounds__(256, 4) void ca_attn(
    const short* __restrict__ qfrag, const short* __restrict__ kfrag,
    const short* __restrict__ vfrag, const short* __restrict__ rpbh,
    short* __restrict__ aob) {
  __shared__ short kv[2][8192];      // dbuf: K tile 8KB | V tile 8KB
  __shared__ short ptile[4][640];    // per-wave 16x32 P chunk (stride 40) / O transpose
  const int bid = blockIdx.x;
  const int b_ = bid >> 5, hh = (bid >> 3) & 3, qt = bid & 7;
  const int bh = b_ * 4 + hh;
  const int tid = threadIdx.x;
  const int w = tid >> 6, lane = tid & 63, lr = lane & 15, lg = lane >> 4;
  const int q0 = qt * 64 + w * 16;

  const short* kg = kfrag + (size_t)bh * 16384;
  const short* vg = vfrag + (size_t)bh * 16384;
  const bf16x8 qf = *(const bf16x8*)(qfrag + ((size_t)bh * 32 + (q0 >> 4)) * 512 + lane * 8);
  const short* bp = rpbh + ((size_t)hh << 18) + (size_t)(q0 + lr) * 512;
  short* pt = &ptile[w][0];

  stage_kv(kg, vg, &kv[0][0], 0, w, lane);
  __syncthreads();  // compiler drains vmcnt before barrier

  float m_run = -1e30f, s_run = 0.f;
  f32x4 o0 = {0.f, 0.f, 0.f, 0.f}, o1 = {0.f, 0.f, 0.f, 0.f};

  for (int T = 0; T < 4; T++) {
    const int cur = T & 1;
    if (T < 3) stage_kv(kg, vg, &kv[cur ^ 1][0], T + 1, w, lane);
    const short* kt = &kv[cur][0];
    const short* vt = &kv[cur][4096];

    // bias loads (bf16, C-in), then QK^T
    u32x2 bw[8];
#pragma unroll
    for (int t = 0; t < 8; t++) bw[t] = *(const u32x2*)(bp + (size_t)T * 128 + t * 16 + lg * 4);
    f32x4 sacc[8];
#pragma unroll
    for (int t = 0; t < 8; t++) {
      f32x4 cin;
      cin[0] = b2f(bw[t].x << 16);
      cin[1] = b2f(bw[t].x & 0xFFFF0000u);
      cin[2] = b2f(bw[t].y << 16);
      cin[3] = b2f(bw[t].y & 0xFFFF0000u);
      bf16x8 kf = *(const bf16x8*)(kt + t * 512 + lane * 8);
      sacc[t] = __builtin_amdgcn_mfma_f32_16x16x32_bf16(kf, qf, cin, 0, 0, 0);
    }
    // lane (lr,lg) holds S[q = q0+lr][j = T*128 + t*16 + lg*4 + r]

    // tile max for q = lr
    float tm = -1e30f;
#pragma unroll
    for (int t = 0; t < 8; t++)
      tm = fmaxf(tm, fmaxf(fmaxf(sacc[t][0], sacc[t][1]), fmaxf(sacc[t][2], sacc[t][3])));
    tm = fmaxf(tm, __shfl_xor(tm, 16));
    tm = fmaxf(tm, __shfl_xor(tm, 32));

    if (T == 0) {
      m_run = tm;
    } else if (__any(tm > m_run + 8.0f)) {  // defer-max (T13)
      float mn = fmaxf(m_run, tm);
      float sc = __builtin_exp2f(m_run - mn);
      s_run *= sc;
      o0 *= sc; o1 *= sc;
      m_run = mn;
    }

    // exp2, sum, pack to bf16 pairs
    unsigned int pw0[8], pw1[8];
#pragma unroll
    for (int t = 0; t < 8; t++) {
      float p0 = __builtin_exp2f(sacc[t][0] - m_run);
      float p1 = __builtin_exp2f(sacc[t][1] - m_run);
      float p2 = __builtin_exp2f(sacc[t][2] - m_run);
      float p3 = __builtin_exp2f(sacc[t][3] - m_run);
      s_run += (p0 + p1) + (p2 + p3);
      pw0[t] = pkbf(p0, p1);
      pw1[t] = pkbf(p2, p3);
    }

    // PV: per 32-j chunk, relayout P through wave-private LDS (no block barrier)
#pragma unroll
    for (int cc = 0; cc < 4; cc++) {
      unsigned long long va = (unsigned long long)pw0[2 * cc] | ((unsigned long long)pw1[2 * cc] << 32);
      unsigned long long vb = (unsigned long long)pw0[2 * cc + 1] | ((unsigned long long)pw1[2 * cc + 1] << 32);
      *(unsigned long long*)(pt + lr * 40 + lg * 4) = va;       // j_local = lg*4+r
      *(unsigned long long*)(pt + lr * 40 + 16 + lg * 4) = vb;  // j_local = 16+lg*4+r
      asm volatile("s_waitcnt lgkmcnt(0)" ::: "memory");
      __builtin_amdgcn_sched_barrier(0);
      bf16x8 paf = *(const bf16x8*)(pt + lr * 40 + lg * 8);
      bf16x8 v0 = *(const bf16x8*)(vt + (cc * 2 + 0) * 512 + lane * 8);
      bf16x8 v1 = *(const bf16x8*)(vt + (cc * 2 + 1) * 512 + lane * 8);
      o0 = __builtin_amdgcn_mfma_f32_16x16x32_bf16(paf, v0, o0, 0, 0, 0);
      o1 = __builtin_amdgcn_mfma_f32_16x16x32_bf16(paf, v1, o1, 0, 0, 0);
    }
    if (T < 3) __syncthreads();  // staging of T+1 complete (vmcnt drained) + buf flip safe
  }

  // final sum reduce + normalize; O[q = lg*4+r][d = {lr, 16+lr}]
  s_run += __shfl_xor(s_run, 16);
  s_run += __shfl_xor(s_run, 32);
  float inv = 1.0f / s_run;  // valid for q = lr on every lane
#pragma unroll
  for (int r = 0; r < 4; r++) {
    float iv = __shfl(inv, lg * 4 + r);
    pt[(lg * 4 + r) * 40 + lr] = f2b(o0[r] * iv);
    pt[(lg * 4 + r) * 40 + 16 + lr] = f2b(o1[r] * iv);
  }
  asm volatile("s_waitcnt lgkmcnt(0)" ::: "memory");
  __builtin_amdgcn_sched_barrier(0);
  {
    const int qq = lane >> 2, pp = lane & 3;
    bf16x8 od = *(const bf16x8*)(pt + qq * 40 + pp * 8);
    *(bf16x8*)(aob + ((size_t)bh * 512 + q0 + qq) * 32 + pp * 8) = od;  // 1KB/wave coalesced
  }
}

// ---------------- K5: output projection ----------------
__global__ __launch_bounds__(256) void ca_proj(
    const short* __restrict__ aob, const short* __restrict__ wp,
    const float* __restrict__ proj_b, float* __restrict__ out) {
  const int t0 = blockIdx.x * 64;
  const int b_ = t0 >> 9, n0 = t0 & 511;
  const int tid = threadIdx.x;
  const int w = tid >> 6, lane = tid & 63, lr = lane & 15, lg = lane >> 4;
  bf16x8 afrag[4];
#pragma unroll
  for (int k4 = 0; k4 < 4; k4++)
    afrag[k4] = *(const bf16x8*)(aob + (((size_t)b_ * 4 + k4) * 512 + n0 + w * 16 + lr) * 32 + lg * 8);
#pragma unroll
  for (int ct = 0; ct < 8; ct++) {
    float bias = proj_b[ct * 16 + lr];
    f32x4 acc = {bias, bias, bias, bias};
    const short* bp = wp + (size_t)(ct * 16 + lr) * 128 + lg * 8;
#pragma unroll
    for (int k4 = 0; k4 < 4; k4++) {
      bf16x8 bfr = *(const bf16x8*)(bp + k4 * 32);
      acc = __builtin_amdgcn_mfma_f32_16x16x32_bf16(afrag[k4], bfr, acc, 0, 0, 0);
    }
#pragma unroll
    for (int r = 0; r < 4; r++)
      out[(size_t)(t0 + w * 16 + lg * 4 + r) * 128 + ct * 16 + lr] = acc[r];
  }
}

extern "C" void kernel_launch(void* const* d_in, const int* in_sizes, int n_in,
                              void* d_out, int out_size, void* d_ws, size_t ws_size,
                              hipStream_t stream) {
  const float* x      = (const float*)d_in[0];
  const float* y      = (const float*)d_in[1];
  const float* qkv_w  = (const float*)d_in[5];
  const float* qkv_b  = (const float*)d_in[6];
  const float* proj_w = (const float*)d_in[7];
  const float* proj_b = (const float*)d_in[8];
  const float* pos_w  = (const float*)d_in[9];
  const float* pos_b  = (const float*)d_in[10];
  const float* ln1g = (const float*)d_in[11];
  const float* ln1b = (const float*)d_in[12];
  const float* p1w  = (const float*)d_in[13];
  const float* p1b  = (const float*)d_in[14];
  const float* ln2g = (const float*)d_in[15];
  const float* ln2b = (const float*)d_in[16];
  const float* p2w  = (const float*)d_in[17];
  const float* p2b  = (const float*)d_in[18];
  const float* ln3g = (const float*)d_in[19];
  const float* ln3b = (const float*)d_in[20];
  const float* p3w  = (const float*)d_in[21];
  const float* p3b  = (const float*)d_in[22];
  float* out = (float*)d_out;

  char* ws = (char*)d_ws;
  short* gq    = (short*)(ws + OFF_Q);
  short* gk    = (short*)(ws + OFF_K);
  short* gv    = (short*)(ws + OFF_V);
  short* rpbh  = (short*)(ws + OFF_RPB);
  short* aob   = (short*)(ws + OFF_AO);
  float* posb  = (float*)(ws + OFF_POS);
  short* wq    = (short*)(ws + OFF_WQ);
  short* wp    = (short*)(ws + OFF_WP);

  ca_convw<<<256, 256, 0, stream>>>(qkv_w, proj_w, wq, wp);
  ca_posmlp<<<53, 64, 0, stream>>>(pos_w, pos_b, ln1g, ln1b, p1w, p1b,
                                   ln2g, ln2b, p2w, p2b, ln3g, ln3b, p3w, p3b, posb);
  ca_rpb<<<1024, 256, 0, stream>>>(posb, rpbh);
  ca_qkv<<<dim3(512, 2), 256, 0, stream>>>(x, y, wq, qkv_b, gq, gk, gv);
  ca_attn<<<2048, 256, 0, stream>>>(gq, gk, gv, rpbh, aob);
  ca_proj<<<512, 256, 0, stream>>>(aob, wp, proj_b, out);
}

// Round 3
// 84.360 us; speedup vs baseline: 2.1398x; 1.3194x over previous
//
#include <hip/hip_runtime.h>
#include <hip/hip_bf16.h>

typedef __attribute__((ext_vector_type(4))) float f32x4;
typedef __attribute__((ext_vector_type(8))) short bf16x8;
typedef __attribute__((ext_vector_type(4))) short bf16x4;
typedef __attribute__((ext_vector_type(2))) unsigned int u32x2;

#define DEV static __device__ __forceinline__

constexpr float LOG2E  = 1.4426950408889634f;
constexpr float QSCALE = 0.17677669529663687f * LOG2E;  // hd^-0.5 * log2e

// ws layout (bytes)
constexpr size_t OFF_Q   = 0;                    // bf16 frag Q  (256 bh x 32 qg x 512)
constexpr size_t OFF_K   = (size_t)8  << 20;     // bf16 frag K  (256 bh x 32 tg x 512)
constexpr size_t OFF_V   = (size_t)16 << 20;     // bf16 frag V  (256 bh x 16 ug x 2 dh x 512), j-permuted
constexpr size_t OFF_RPB = (size_t)24 << 20;     // bf16 frag bias (4 h x 32 qg x 32 jc x 64 lane x 4)
constexpr size_t OFF_AO  = (size_t)27 << 20;     // bf16 head-major (bh, n, 32)
constexpr size_t OFF_POS = (size_t)35 << 20;     // f32  (3375, 4)
constexpr size_t OFF_WQ  = (size_t)36 << 20;     // bf16 (384, 128)
constexpr size_t OFF_WP  = (size_t)37 << 20;     // bf16 (128, 128)

DEV short f2b(float f) {
  union { __bf16 h; short s; } u;
  u.h = (__bf16)f;
  return u.s;
}
DEV float b2f(unsigned int u) {
  union { unsigned int u; float f; } x; x.u = u; return x.f;
}
DEV unsigned int pkbf(float a, float b) {
  union { __bf16 h; unsigned short s; } ua, ub;
  ua.h = (__bf16)a; ub.h = (__bf16)b;
  return (unsigned int)ua.s | ((unsigned int)ub.s << 16);
}

// ---------------- K0: fused weight convert + DynamicPosBias MLP ----------------
DEV void ln_relu8(const float* v, const float* __restrict__ g,
                  const float* __restrict__ b, float* t) {
  float m = 0.f;
#pragma unroll
  for (int i = 0; i < 8; i++) m += v[i];
  m *= 0.125f;
  float var = 0.f;
#pragma unroll
  for (int i = 0; i < 8; i++) { float d = v[i] - m; var += d * d; }
  var *= 0.125f;
  float inv = 1.0f / sqrtf(var + 1e-5f);
#pragma unroll
  for (int i = 0; i < 8; i++) {
    float u = (v[i] - m) * inv * g[i] + b[i];
    t[i] = u > 0.f ? u : 0.f;
  }
}

DEV void mm8(const float* t, const float* __restrict__ w,
             const float* __restrict__ c, float* o) {
#pragma unroll
  for (int oo = 0; oo < 8; oo++) {
    float a = c[oo];
#pragma unroll
    for (int i = 0; i < 8; i++) a += t[i] * w[oo * 8 + i];
    o[oo] = a;
  }
}

__global__ void ca_setup(
    const float* __restrict__ qkv_w, const float* __restrict__ proj_w,
    short* __restrict__ wq, short* __restrict__ wp,
    const float* __restrict__ pw, const float* __restrict__ pb,
    const float* __restrict__ g1, const float* __restrict__ b1,
    const float* __restrict__ w1, const float* __restrict__ c1,
    const float* __restrict__ g2, const float* __restrict__ b2,
    const float* __restrict__ w2, const float* __restrict__ c2,
    const float* __restrict__ g3, const float* __restrict__ b3,
    const float* __restrict__ w3, const float* __restrict__ c3,
    float* __restrict__ pos_out) {
  const int blk = blockIdx.x;
  if (blk < 256) {
    int i = blk * 256 + threadIdx.x;  // 65536 threads
    if (i < 49152) {
      float f = qkv_w[i];
      if (i < 16384) f *= QSCALE;  // q rows: fold scale*log2e
      wq[i] = f2b(f);
    } else {
      int j = i - 49152;
      wp[j] = f2b(proj_w[j]);
    }
    return;
  }
  int r = (blk - 256) * 256 + threadIdx.x;
  if (r >= 3375) return;
  float x0 = (float)(r / 225 - 7);
  float x1 = (float)((r / 15) % 15 - 7);
  float x2 = (float)(r % 15 - 7);
  float v[8], t[8], u[8];
#pragma unroll
  for (int o = 0; o < 8; o++)
    v[o] = x0 * pw[o * 3] + x1 * pw[o * 3 + 1] + x2 * pw[o * 3 + 2] + pb[o];
  ln_relu8(v, g1, b1, t);
  mm8(t, w1, c1, u);
  ln_relu8(u, g2, b2, t);
  mm8(t, w2, c2, v);
  ln_relu8(v, g3, b3, t);
#pragma unroll
  for (int hh = 0; hh < 4; hh++) {
    float a = c3[hh];
#pragma unroll
    for (int i = 0; i < 8; i++) a += t[i] * w3[hh * 8 + i];
    pos_out[r * 4 + hh] = a * LOG2E;  // log2 domain for exp2-softmax
  }
}

// ---------------- K1: expand rpb table into MFMA-C fragment order, bf16 ----------------
// rpbf[(((hh*32+qg)*32 + jc)*64 + lane)*4 + r] = bias[q=qg*16+(lane&15)][j=jc*16+(lane>>4)*4+r]
__global__ void ca_rpb(const float* __restrict__ pos, short* __restrict__ rpbf) {
  int gid = blockIdx.x * 256 + threadIdx.x;  // 262144 threads
  int lane = gid & 63, jc = (gid >> 6) & 31, qg = (gid >> 11) & 31, hh = gid >> 16;
  int q = qg * 16 + (lane & 15);
  int j0 = jc * 16 + (lane >> 4) * 4;
  bf16x4 outv;
#pragma unroll
  for (int r = 0; r < 4; r++) {
    int j = j0 + r;
    int rh = (q >> 6) - (j >> 6) + 7;
    int rw = ((q >> 3) & 7) - ((j >> 3) & 7) + 7;
    int rd = (q & 7) - (j & 7) + 7;
    int idx = (rh * 15 + rw) * 15 + rd;
    outv[r] = f2b(pos[idx * 4 + hh]);
  }
  *(bf16x4*)(rpbf + (size_t)gid * 4) = outv;
}

// ---------------- K2: QKV projection -> frag-order Q/K/V ----------------
// z=0: x -> qfrag; z=1: y -> kfrag + vfrag (V with PV j-permutation baked in)
__global__ __launch_bounds__(256) void ca_qkv(
    const float* __restrict__ x, const float* __restrict__ y,
    const short* __restrict__ wq, const float* __restrict__ qkv_b,
    short* __restrict__ gq, short* __restrict__ gk, short* __restrict__ gv) {
  __shared__ short lds[16384];  // 32KB: input stage (stride 136), then frag relayout
  const int z = blockIdx.y;
  const int t0 = blockIdx.x * 64;
  const int b_ = t0 >> 9;
  const int n0 = t0 & 511;
  const int tid = threadIdx.x;
  const float* __restrict__ in = (z == 0) ? x : y;
  // coalesced input staging: flat f32x4 per thread
#pragma unroll
  for (int i = 0; i < 8; i++) {
    int flat = i * 1024 + tid * 4;
    f32x4 f = *(const f32x4*)(in + (size_t)t0 * 128 + flat);
    int row = flat >> 7, col = flat & 127;
    bf16x4 hv;
#pragma unroll
    for (int e = 0; e < 4; e++) hv[e] = f2b(f[e]);
    *(bf16x4*)(lds + row * 136 + col) = hv;
  }
  __syncthreads();
  const int w = tid >> 6, lane = tid & 63, lr = lane & 15, lg = lane >> 4;
  bf16x8 afrag[4];
  {
    const short* ap = lds + (w * 16 + lr) * 136 + lg * 8;
#pragma unroll
    for (int k4 = 0; k4 < 4; k4++) afrag[k4] = *(const bf16x8*)(ap + k4 * 32);
  }
  __syncthreads();  // all afrag reads done before relayout overwrites lds

  const int nct = z ? 16 : 8;
  for (int ct = 0; ct < nct; ct++) {
    const int col = z * 128 + ct * 16;
    float bias = qkv_b[col + lr];
    if (z == 0) bias *= QSCALE;
    f32x4 acc = {bias, bias, bias, bias};
    const short* bp = wq + (size_t)(col + lr) * 128 + lg * 8;
#pragma unroll
    for (int k4 = 0; k4 < 4; k4++) {
      bf16x8 bfr = *(const bf16x8*)(bp + k4 * 32);
      acc = __builtin_amdgcn_mfma_f32_16x16x32_bf16(afrag[k4], bfr, acc, 0, 0, 0);
    }
    // acc[r] = out[token = t0 + w*16 + lg*4 + r][col + lr]
    if (z == 1 && ct >= 8) {
      // V frag (PV A-operand-compatible j-permuted layout):
      // region [hh(4)][ul(2)][dh(2)][lane(64)][e(8)]; lane_v = lane; e = (w&1)*4 + r
      const int hv_ = (ct - 8) >> 1;
      const int dh = (ct - 8) & 1;
      const int base = 8192 + (((hv_ * 2 + (w >> 1)) * 2 + dh) * 512) + lane * 8 + (w & 1) * 4;
      *(unsigned int*)(lds + base)     = pkbf(acc[0], acc[1]);
      *(unsigned int*)(lds + base + 2) = pkbf(acc[2], acc[3]);
    } else {  // Q or K: chunk (w*4 + ct>>1), lane=(n&15)+16*(d>>3), e=d&7
      const int d = (ct & 1) * 16 + lr;
      const int base = (w * 4 + (ct >> 1)) * 512 + 128 * (d >> 3) + (d & 7);
#pragma unroll
      for (int r = 0; r < 4; r++)
        lds[base + (lg * 4 + r) * 8] = f2b(acc[r]);
    }
  }
  __syncthreads();
  // cooperative 1KB-per-wave coalesced chunk stores
  if (z == 0) {
#pragma unroll
    for (int kk = 0; kk < 4; kk++) {
      const int c = kk * 4 + w, hh = c & 3, tg = c >> 2;
      bf16x8 vd = *(const bf16x8*)(lds + c * 512 + lane * 8);
      *(bf16x8*)(gq + (((size_t)b_ * 4 + hh) * 32 + (n0 >> 4) + tg) * 512 + lane * 8) = vd;
    }
  } else {
#pragma unroll
    for (int kk = 0; kk < 4; kk++) {
      const int c = kk * 4 + w, hh = c & 3, tg = c >> 2;
      bf16x8 vd = *(const bf16x8*)(lds + c * 512 + lane * 8);
      *(bf16x8*)(gk + (((size_t)b_ * 4 + hh) * 32 + (n0 >> 4) + tg) * 512 + lane * 8) = vd;
    }
#pragma unroll
    for (int kk = 0; kk < 4; kk++) {
      const int c = kk * 4 + w, hh = c >> 2, ul = (c >> 1) & 1, dh = c & 1;
      bf16x8 vd = *(const bf16x8*)(lds + 8192 + c * 512 + lane * 8);
      *(bf16x8*)(gv + ((((size_t)b_ * 4 + hh) * 16 + (n0 >> 5) + ul) * 2 + dh) * 512 + lane * 8) = vd;
    }
  }
}

// ---------------- K3: fused attention ----------------
DEV void stage_kv(const short* kg, const short* vg, short* buf, int T, int w, int lane) {
#pragma unroll
  for (int i = 0; i < 4; i++) {
    const int c = w * 4 + i;
    const short* src;
    short* dst;
    if (c < 8) {
      src = kg + ((size_t)(T * 8 + c)) * 512 + lane * 8;
      dst = buf + c * 512;
    } else {
      src = vg + ((size_t)(T * 8 + c - 8)) * 512 + lane * 8;
      dst = buf + 4096 + (c - 8) * 512;
    }
    __builtin_amdgcn_global_load_lds((const __attribute__((address_space(1))) void*)src,
                                     (__attribute__((address_space(3))) void*)dst, 16, 0, 0);
  }
}

__global__ __launch_bounds__(256, 4) void ca_attn(
    const short* __restrict__ qfrag, const short* __restrict__ kfrag,
    const short* __restrict__ vfrag, const short* __restrict__ rpbf,
    short* __restrict__ aob) {
  __shared__ short kv[2][8192];  // dbuf: K tile 8KB | V tile 8KB (per buf 16KB)
  const int bid = blockIdx.x;
  // XCD swizzle: the 8 qt-blocks of one (b,h) share bid%256 -> same XCD slot
  const int qt = bid >> 8, rem = bid & 255;
  const int b_ = rem >> 2, hh = rem & 3;
  const int bh = b_ * 4 + hh;
  const int tid = threadIdx.x;
  const int w = tid >> 6, lane = tid & 63, lg = lane >> 4;
  const int q0 = qt * 64 + w * 16, qg = (q0 >> 4);

  const short* kg = kfrag + (size_t)bh * 16384;
  const short* vg = vfrag + (size_t)bh * 16384;
  const bf16x8 qf = *(const bf16x8*)(qfrag + ((size_t)bh * 32 + qg) * 512 + lane * 8);
  const short* bp = rpbf + ((size_t)(hh * 32 + qg) << 13) + lane * 4;

  union PU { bf16x8 v; unsigned int u[4]; };
  PU ones;
  ones.u[0] = 0x3F803F80u; ones.u[1] = 0x3F803F80u;
  ones.u[2] = 0x3F803F80u; ones.u[3] = 0x3F803F80u;

  stage_kv(kg, vg, &kv[0][0], 0, w, lane);
  __syncthreads();

  f32x4 o0 = {0.f, 0.f, 0.f, 0.f}, o1 = {0.f, 0.f, 0.f, 0.f}, o2 = {0.f, 0.f, 0.f, 0.f};

  for (int T = 0; T < 4; T++) {
    const int cur = T & 1;
    if (T < 3) stage_kv(kg, vg, &kv[cur ^ 1][0], T + 1, w, lane);
    const short* kt = &kv[cur][0];
    const short* vt = &kv[cur][4096];

    u32x2 bw[8];
#pragma unroll
    for (int t = 0; t < 8; t++) bw[t] = *(const u32x2*)(bp + (size_t)(T * 8 + t) * 256);

#pragma unroll
    for (int uu = 0; uu < 4; uu++) {
      PU p;
#pragma unroll
      for (int half = 0; half < 2; half++) {
        const int t = uu * 2 + half;
        bf16x8 kf = *(const bf16x8*)(kt + t * 512 + lane * 8);
        f32x4 cin;
        cin[0] = b2f(bw[t].x << 16);
        cin[1] = b2f(bw[t].x & 0xFFFF0000u);
        cin[2] = b2f(bw[t].y << 16);
        cin[3] = b2f(bw[t].y & 0xFFFF0000u);
        f32x4 s = __builtin_amdgcn_mfma_f32_16x16x32_bf16(kf, qf, cin, 0, 0, 0);
        // no-max softmax: scores bounded (|s| < ~1), exp2 direct is exact-ratio
        p.u[half * 2 + 0] = pkbf(__builtin_exp2f(s[0]), __builtin_exp2f(s[1]));
        p.u[half * 2 + 1] = pkbf(__builtin_exp2f(s[2]), __builtin_exp2f(s[3]));
      }
      bf16x8 vf0 = *(const bf16x8*)(vt + (uu * 2 + 0) * 512 + lane * 8);
      bf16x8 vf1 = *(const bf16x8*)(vt + (uu * 2 + 1) * 512 + lane * 8);
      o0 = __builtin_amdgcn_mfma_f32_16x16x32_bf16(p.v, vf0, o0, 0, 0, 0);
      o1 = __builtin_amdgcn_mfma_f32_16x16x32_bf16(p.v, vf1, o1, 0, 0, 0);
      o2 = __builtin_amdgcn_mfma_f32_16x16x32_bf16(p.v, ones.v, o2, 0, 0, 0);
    }
    if (T < 3) __syncthreads();
  }

  // epilogue: o2[r] = row-sum for q = lg*4+r (all lanes); normalize + transpose via LDS
  // kv[0] is dead here (last tile used kv[1]); wave-private regions
  short* pt = &kv[0][w * 1024];
  const int lr = lane & 15;
#pragma unroll
  for (int r = 0; r < 4; r++) {
    float iv = 1.0f / o2[r];
    pt[(lg * 4 + r) * 40 + lr] = f2b(o0[r] * iv);
    pt[(lg * 4 + r) * 40 + 16 + lr] = f2b(o1[r] * iv);
  }
  asm volatile("s_waitcnt lgkmcnt(0)" ::: "memory");
  __builtin_amdgcn_sched_barrier(0);
  {
    const int qq = lane >> 2, pp = lane & 3;
    bf16x8 od = *(const bf16x8*)(pt + qq * 40 + pp * 8);
    *(bf16x8*)(aob + ((size_t)bh * 512 + q0 + qq) * 32 + pp * 8) = od;  // 1KB/wave coalesced
  }
}

// ---------------- K4: output projection ----------------
__global__ __launch_bounds__(256) void ca_proj(
    const short* __restrict__ aob, const short* __restrict__ wp,
    const float* __restrict__ proj_b, float* __restrict__ out) {
  const int t0 = blockIdx.x * 64;
  const int b_ = t0 >> 9, n0 = t0 & 511;
  const int tid = threadIdx.x;
  const int w = tid >> 6, lane = tid & 63, lr = lane & 15, lg = lane >> 4;
  bf16x8 afrag[4];
#pragma unroll
  for (int k4 = 0; k4 < 4; k4++)
    afrag[k4] = *(const bf16x8*)(aob + (((size_t)b_ * 4 + k4) * 512 + n0 + w * 16 + lr) * 32 + lg * 8);
#pragma unroll
  for (int ct = 0; ct < 8; ct++) {
    float bias = proj_b[ct * 16 + lr];
    f32x4 acc = {bias, bias, bias, bias};
    const short* bp = wp + (size_t)(ct * 16 + lr) * 128 + lg * 8;
#pragma unroll
    for (int k4 = 0; k4 < 4; k4++) {
      bf16x8 bfr = *(const bf16x8*)(bp + k4 * 32);
      acc = __builtin_amdgcn_mfma_f32_16x16x32_bf16(afrag[k4], bfr, acc, 0, 0, 0);
    }
#pragma unroll
    for (int r = 0; r < 4; r++)
      out[(size_t)(t0 + w * 16 + lg * 4 + r) * 128 + ct * 16 + lr] = acc[r];
  }
}

extern "C" void kernel_launch(void* const* d_in, const int* in_sizes, int n_in,
                              void* d_out, int out_size, void* d_ws, size_t ws_size,
                              hipStream_t stream) {
  const float* x      = (const float*)d_in[0];
  const float* y      = (const float*)d_in[1];
  const float* qkv_w  = (const float*)d_in[5];
  const float* qkv_b  = (const float*)d_in[6];
  const float* proj_w = (const float*)d_in[7];
  const float* proj_b = (const float*)d_in[8];
  const float* pos_w  = (const float*)d_in[9];
  const float* pos_b  = (const float*)d_in[10];
  const float* ln1g = (const float*)d_in[11];
  const float* ln1b = (const float*)d_in[12];
  const float* p1w  = (const float*)d_in[13];
  const float* p1b  = (const float*)d_in[14];
  const float* ln2g = (const float*)d_in[15];
  const float* ln2b = (const float*)d_in[16];
  const float* p2w  = (const float*)d_in[17];
  const float* p2b  = (const float*)d_in[18];
  const float* ln3g = (const float*)d_in[19];
  const float* ln3b = (const float*)d_in[20];
  const float* p3w  = (const float*)d_in[21];
  const float* p3b  = (const float*)d_in[22];
  float* out = (float*)d_out;

  char* ws = (char*)d_ws;
  short* gq    = (short*)(ws + OFF_Q);
  short* gk    = (short*)(ws + OFF_K);
  short* gv    = (short*)(ws + OFF_V);
  short* rpbf  = (short*)(ws + OFF_RPB);
  short* aob   = (short*)(ws + OFF_AO);
  float* posb  = (float*)(ws + OFF_POS);
  short* wq    = (short*)(ws + OFF_WQ);
  short* wp    = (short*)(ws + OFF_WP);

  ca_setup<<<270, 256, 0, stream>>>(qkv_w, proj_w, wq, wp,
                                    pos_w, pos_b, ln1g, ln1b, p1w, p1b,
                                    ln2g, ln2b, p2w, p2b, ln3g, ln3b, p3w, p3b, posb);
  ca_rpb<<<1024, 256, 0, stream>>>(posb, rpbf);
  ca_qkv<<<dim3(512, 2), 256, 0, stream>>>(x, y, wq, qkv_b, gq, gk, gv);
  ca_attn<<<2048, 256, 0, stream>>>(gq, gk, gv, rpbf, aob);
  ca_proj<<<512, 256, 0, stream>>>(aob, wp, proj_b, out);
}